// Round 11
// baseline (580.029 us; speedup 1.0000x reference)
//
#include <hip/hip_runtime.h>
#include <math.h>
#include <stdint.h>

// SLAYER 2-layer SNN. Round 23: manual register double-buffer in gemm K-loop.
//   expand_x -> decompose_i8 x2 ->
//   fused_gc<1024> -> scan<BITS->Bexp2> -> fused_gc<2048> -> scan<F32>.
// R22 post-mortem: fusion landed (574us best; WRITE exactly 131072 KB,
// VGPR 84, occ 32%). fused<1024> = 200us = gemm ~132 + conv ~50 + LDS
// conflicts (~12us, counter 7.2M -- noted). Gemm phase still R20's story:
// unroll-1 K-loop exposes ~200cyc L2 latency per s-iter (MfmaUtil 18.5 =
// pipe idle 81%); R21 proved 'unroll 2' won't lift loads over the
// back-edge. R23: hand-pipeline -- preload s=0, each iter loads afn/bfn
// (s+1) into FRESH regs before the 10 MFMAs on af/bf, copy after. Load
// latency of s+1 overlaps matrix-pipe time of s (~200cyc each). Live:
// acc40 + 28 + 28 + addr ~111 < 128 cap. Last iter reloads s (harmless).
// Gate: WRITE_SIZE exactly 131072 KB; if VGPR=128+spill, revert prefetch.
// Numerics byte-identical (absmax 0.0): per-chain MFMA order unchanged.

#define TT     256
#define KLEN   62
#define THETA  10.0

typedef int v4i __attribute__((ext_vector_type(4)));

// ===================== expand x -> i8 B-matrix (layer 1) ====================
// x: [32][1024][256] f32 {0,1}; bexp: [b][g=i/16][t][m=i%16] i8 {0,1}
__global__ __launch_bounds__(256)
void expand_x(const float* __restrict__ x, signed char* __restrict__ bexp)
{
    const int b = blockIdx.x;
    const int g = blockIdx.y;             // 64 groups of 16 inputs
    const int t = threadIdx.x;
    const float* xp = x + ((size_t)b*1024 + g*16)*TT + t;
    uint32_t uu[4];
    #pragma unroll
    for (int j = 0; j < 4; ++j) {
        uint32_t w = 0;
        #pragma unroll
        for (int m = 0; m < 4; ++m)
            w |= (xp[(size_t)(j*4 + m)*TT] >= 0.5f) ? (1u << (8*m)) : 0u;
        uu[j] = w;
    }
    *(uint4*)(bexp + (((size_t)b*64 + g)*256 + t)*16) = *(const uint4*)uu;
}

// ====================== weight -> int8 digit planes (swizzled) ==============
// planes: [oblk][s(I/64)][p(5)][lane(64)][16 B] -- MFMA A-frag register order:
// lane = quad*16+col holds digits of w[oblk*16+col][s*64 + quad*16 + 0..15].
__global__ __launch_bounds__(256)
void decompose_i8(const float* __restrict__ w, signed char* __restrict__ planes,
                  int I, int total)
{
    const int f = blockIdx.x * 256 + threadIdx.x;
    if (f >= total) return;
    const int NS = I / 64;
    const int per_oblk = NS * 5120;
    int rem  = f;
    const int oblk = rem / per_oblk;  rem -= oblk * per_oblk;
    const int s    = rem / 5120;      rem -= s * 5120;
    const int p    = rem >> 10;
    const int l    = (rem & 1023) >> 4;
    const int j    = rem & 15;
    const int quad = l >> 4, col = l & 15;
    const float wv = w[(size_t)(oblk*16 + col) * I + s*64 + quad*16 + j];
    long long v = llrint((double)wv * 274877906944.0);   // w * 2^38, exact int
    int d = 0;
    for (int q = 0; q <= p; ++q) {                       // balanced base-256
        d = (int)((v + 128) & 255) - 128;
        v = (v - d) >> 8;
    }
    planes[f] = (signed char)d;
}

// ====================== fused gemm+conv kernel ==============================
// grid (B, O/16): b fastest (A-planes L2-hot). Phase 1: two-pass acc[5][2]
// i8 MFMA with MANUAL register double-buffer (afn/bfn prefetch of s+1
// issued before the MFMAs of s) -> exact fp64 recombine into a_lds.
// Barrier. Phase 2: verified 61-tap FIR (pass unroll 1, R20-proven) -> u.
// Max live ~111 < 128 cap -> 4 waves/SIMD retained.
template<int I>
__global__ __launch_bounds__(256) __attribute__((amdgpu_num_vgpr(128)))
void fused_gc(const signed char* __restrict__ bexp,    // [b][I/16][256][16]
              const signed char* __restrict__ planes,  // swizzled A planes
              double*            __restrict__ u,       // [B][256][OS]
              int OS)
{
    constexpr int NS = I / 64;
    __shared__ double a_lds[257 * 17];                   // 34.95 KB (row 256 = 0)
    __shared__ double srmE[68];

    const int tid  = threadIdx.x;
    const int lane = tid & 63;
    const int wvu  = tid >> 6;
    const int quad = lane >> 4;
    const int col  = lane & 15;
    const int b    = blockIdx.x;
    const int oblk = blockIdx.y;
    const int o0   = oblk * 16;
    const int tw   = wvu * 64;

    if (tid < 68) {
        const int k = tid - 2;
        double v = 0.0;
        if (k >= 1 && k <= 61) {
            double wv = (double)k / 8.0 * exp(1.0 - (double)k / 8.0);
            v = (double)(float)wv;     // fp32-rounded tap, widened (R1-R22)
        }
        srmE[tid] = v;
    }

    // ---------------- phase 1: gemm with manual K-prefetch ------------------
    const signed char* Apg = planes + (size_t)oblk * NS * 5120 + lane * 16;
    const double inv = 1.0 / 274877906944.0;             // 2^-38

    #pragma unroll 1
    for (int half = 0; half < 2; ++half) {
        const signed char* Bx = bexp +
            (((size_t)b*(I/16) + quad)*256 + tw + half*32 + col)*16;

        v4i acc[5][2];
        #pragma unroll
        for (int p = 0; p < 5; ++p)
            #pragma unroll
            for (int nt = 0; nt < 2; ++nt)
                acc[p][nt] = (v4i){0, 0, 0, 0};

        // preload s = 0
        v4i af[5], bf[2];
        #pragma unroll
        for (int p = 0; p < 5; ++p)
            af[p] = *(const v4i*)(const void*)(Apg + p * 1024);
        #pragma unroll
        for (int nt = 0; nt < 2; ++nt)
            bf[nt] = *(const v4i*)(const void*)(Bx + nt * 256);

        #pragma unroll 1
        for (int s = 0; s < NS; ++s) {
            // prefetch s+1 into fresh registers (independent of the MFMAs)
            const int sn = (s + 1 < NS) ? s + 1 : s;
            v4i afn[5], bfn[2];
            #pragma unroll
            for (int p = 0; p < 5; ++p)
                afn[p] = *(const v4i*)(const void*)(Apg + (size_t)sn * 5120 + p * 1024);
            #pragma unroll
            for (int nt = 0; nt < 2; ++nt)
                bfn[nt] = *(const v4i*)(const void*)(Bx + (size_t)sn * 16384 + nt * 256);

            // compute on current set while the prefetch is in flight
            #pragma unroll
            for (int nt = 0; nt < 2; ++nt)
                #pragma unroll
                for (int p = 0; p < 5; ++p)
                    acc[p][nt] = __builtin_amdgcn_mfma_i32_16x16x64_i8(
                                     af[p], bf[nt], acc[p][nt], 0, 0, 0);

            #pragma unroll
            for (int p = 0; p < 5; ++p) af[p] = afn[p];
            #pragma unroll
            for (int nt = 0; nt < 2; ++nt) bf[nt] = bfn[nt];
        }

        // recombine: exact fp64 a into LDS (verified mapping)
        #pragma unroll
        for (int nt = 0; nt < 2; ++nt) {
            const int t = tw + half*32 + nt*16 + col;
            #pragma unroll
            for (int r = 0; r < 4; ++r) {
                double v =            (double)acc[4][nt][r];
                v = v * 256.0 + (double)acc[3][nt][r];
                v = v * 256.0 + (double)acc[2][nt][r];
                v = v * 256.0 + (double)acc[1][nt][r];
                v = v * 256.0 + (double)acc[0][nt][r];
                a_lds[t * 17 + quad*4 + r] = v * inv;
            }
        }
    }

    if (tid < 17) a_lds[256 * 17 + tid] = 0.0;           // zero-guard row
    __syncthreads();                                     // the only barrier

    // ---------------- phase 2: conv (R20-proven serialized body) ------------
    const int o    = tid & 15;
    const int tgrp = tid >> 4;                           // 0..15
    #pragma unroll 1
    for (int pass = 0; pass < 4; ++pass) {
        const int T0b = pass * 64 + tgrp * 4;
        double u0 = 0, u1 = 0, u2 = 0, u3 = 0;
        double w1 = srmE[64], w2 = srmE[65], w3 = srmE[66];   // zero pads
        for (int d = 0; d < 64; d += 4) {
            const int row = T0b - 61 + d;
            const int r0 = (row + 0 < 0) ? 256 : row + 0;
            const int r1 = (row + 1 < 0) ? 256 : row + 1;
            const int r2 = (row + 2 < 0) ? 256 : row + 2;
            const int r3 = (row + 3 < 0) ? 256 : row + 3;
            const double av0 = a_lds[r0 * 17 + o];
            const double av1 = a_lds[r1 * 17 + o];
            const double av2 = a_lds[r2 * 17 + o];
            const double av3 = a_lds[r3 * 17 + o];
            const double n0 = srmE[63 - d], n1 = srmE[62 - d];
            const double n2 = srmE[61 - d], n3 = srmE[60 - d];
            u0 = fma(n0, av0, u0); u1 = fma(w1, av0, u1); u2 = fma(w2, av0, u2); u3 = fma(w3, av0, u3);
            u0 = fma(n1, av1, u0); u1 = fma(n0, av1, u1); u2 = fma(w1, av1, u2); u3 = fma(w2, av1, u3);
            u0 = fma(n2, av2, u0); u1 = fma(n1, av2, u1); u2 = fma(n0, av2, u2); u3 = fma(w1, av2, u3);
            u0 = fma(n3, av3, u0); u1 = fma(n2, av3, u1); u2 = fma(n1, av3, u2); u3 = fma(n0, av3, u3);
            w1 = n3; w2 = n2; w3 = n1;
        }
        double* up = u + ((size_t)b * 256 + T0b) * OS + o0 + o;
        up[0]              = u0;
        up[(size_t)OS]     = u1;
        up[(size_t)OS * 2] = u2;
        up[(size_t)OS * 3] = u3;
    }
}

// ========================== scan (R8/R10-verified core) =====================
// lane = neuron; 256 sequential steps; refractory via 61-bit history mask.
// FINAL=false: ballots -> expanded i8 B-matrix bexp_out[b][g][t][m].
// FINAL=true:  f32 out[b][o][t].
template<bool FINAL>
__global__ __launch_bounds__(256)
void scan_spikes(const double* __restrict__ u, signed char* __restrict__ bexp_out,
                 float* __restrict__ f32_out, int OS)
{
    __shared__ double   ref64[KLEN];
    __shared__ uint32_t blds[8][256];   // 8 KB ballot staging
    const int tid = threadIdx.x;
    if (tid < KLEN) {
        double v = (double)tid / 8.0 * exp(1.0 - (double)tid / 8.0);
        ref64[tid] = (double)(float)(-20.0 * v);
    }
    __syncthreads();

    const int b     = blockIdx.y;
    const int obase = blockIdx.x * 256;
    const int o     = obase + tid;
    const int lane  = tid & 63;
    const int wv    = tid >> 6;
    const double* up = u + (size_t)b * TT * OS + o;

    uint64_t mask = 0;
    double cur0 = up[0], cur1 = up[OS], cur2 = up[2 * (size_t)OS], cur3 = up[3 * (size_t)OS];
    for (int t0 = 0; t0 < TT; t0 += 4) {
        double nx0 = 0, nx1 = 0, nx2 = 0, nx3 = 0;
        if (t0 + 4 < TT) {
            const double* pp = up + (size_t)(t0 + 4) * OS;
            nx0 = pp[0]; nx1 = pp[OS]; nx2 = pp[2 * (size_t)OS]; nx3 = pp[3 * (size_t)OS];
        }
        #pragma unroll
        for (int q = 0; q < 4; ++q) {
            const double uv = (q == 0) ? cur0 : (q == 1) ? cur1 : (q == 2) ? cur2 : cur3;
            uint64_t m = mask;
            double r0 = 0.0, r1 = 0.0;
            while (m) {
                int p = __builtin_ctzll(m); m &= m - 1;
                r0 += ref64[p + 1];
                if (m) { int pq = __builtin_ctzll(m); m &= m - 1; r1 += ref64[pq + 1]; }
            }
            const bool s = (uv + (r0 + r1)) >= THETA;
            const uint64_t bal = __ballot(s);
            if (lane == 0) {
                blds[wv * 2 + 0][t0 + q] = (uint32_t)bal;
                blds[wv * 2 + 1][t0 + q] = (uint32_t)(bal >> 32);
            }
            mask = ((mask << 1) | (s ? 1ull : 0ull)) & ((1ull << 61) - 1ull);
        }
        cur0 = nx0; cur1 = nx1; cur2 = nx2; cur3 = nx3;
    }
    __syncthreads();

    if (!FINAL) {
        // expand ballots to i8 B-matrix: entry g = obase/16 + gl, byte m =
        // bit ((gl&1)*16 + m) of word blds[gl>>1][t]  (i = g*16 + m)
        const int gbase = obase >> 4;
        for (int e = tid; e < 16 * 256; e += 256) {
            const int gl = e >> 8, t = e & 255;
            const uint32_t w = blds[gl >> 1][t];
            const uint32_t h = (w >> ((gl & 1) * 16)) & 0xFFFFu;
            uint32_t uu[4];
            #pragma unroll
            for (int j = 0; j < 4; ++j)
                uu[j] = (((h >> (4*j)) & 0xFu) * 0x00204081u) & 0x01010101u;
            *(uint4*)(bexp_out + (((size_t)b*128 + gbase + gl)*256 + t)*16) =
                *(const uint4*)uu;
        }
    } else {
        for (int ol = 0; ol < 256; ++ol) {
            const uint32_t w = blds[ol >> 5][tid];
            f32_out[((size_t)b * 512 + obase + ol) * TT + tid] =
                (float)((w >> (ol & 31)) & 1u);
        }
    }
}

// ================================ launcher ==================================
extern "C" void kernel_launch(void* const* d_in, const int* in_sizes, int n_in,
                              void* d_out, int out_size, void* d_ws, size_t ws_size,
                              hipStream_t stream)
{
    const float* x  = (const float*)d_in[0];   // [32][1024][256]
    const float* w1 = (const float*)d_in[1];   // [2048][1024]
    const float* w2 = (const float*)d_in[2];   // [512][2048]
    float* out = (float*)d_out;                // [32][512][256]

    char* ws = (char*)d_ws;
    // liveness-based layout (Bexp2 aliases dead P1/Bexp1): total ~158 MB
    signed char* P2    = (signed char*)ws;                      // 5.25 MB
    size_t roff = (size_t)32 * 32 * 5120;                       // 5242880
    signed char* P1    = (signed char*)(ws + roff);             // 10.5 MB
    signed char* Bexp1 = (signed char*)(ws + roff + (size_t)128*16*5120); // 8 MB
    signed char* Bexp2 = (signed char*)(ws + roff);             // 16 MB (alias)
    size_t uoff = roff + (size_t)128*16*5120 + (size_t)32*64*256*16; // 24117248
    double* uBuf = (double*)(ws + uoff);                        // 134 MB

    expand_x<<<dim3(32, 64), 256, 0, stream>>>(x, Bexp1);
    decompose_i8<<<dim3((10485760 + 255)/256), 256, 0, stream>>>(w1, P1, 1024, 10485760);
    decompose_i8<<<dim3((5242880  + 255)/256), 256, 0, stream>>>(w2, P2, 2048, 5242880);

    // layer 1: 1024 -> 2048  (fused gemm+conv: u written directly)
    fused_gc<1024><<<dim3(32, 128), 256, 0, stream>>>(Bexp1, P1, uBuf, 2048);
    scan_spikes<false><<<dim3(8, 32), 256, 0, stream>>>(uBuf, Bexp2, nullptr, 2048);
    // layer 2: 2048 -> 512
    fused_gc<2048><<<dim3(32, 32), 256, 0, stream>>>(Bexp2, P2, uBuf, 512);
    scan_spikes<true><<<dim3(2, 32), 256, 0, stream>>>(uBuf, nullptr, out, 512);
}

// Round 12
// 537.799 us; speedup vs baseline: 1.0785x; 1.0785x over previous
//
#include <hip/hip_runtime.h>
#include <math.h>
#include <stdint.h>

// SLAYER 2-layer SNN. Round 24: LDS write-swizzle + scan prefetch/spread.
//   expand_x -> decompose_i8 x2 ->
//   fused_gc<1024> -> scan<BITS->Bexp2> -> fused_gc<2048> -> scan<F32>.
// R23 post-mortem: manual K-prefetch was ELIDED (VGPR stayed 84, VALU
// 40->50 = copies became movs, loads not in flight) -- consistent with
// learn_hip m99-m141: source-level pipelining is null on this compiler.
// Reverted. R24 targets the counters instead:
// (1) SQ_LDS_BANK_CONFLICT 7.18M in fused_gc = recombine WRITES: bank
//     (t+4q+r)%16 hits each residue 4x -> 4-way. Fix: store (t,j) at
//     column (j + 4(t&3))&15 -> write banks col+4(col&3)+4q = permutation
//     per quarter-wave (conflict-free, chunks stay 32B contiguous); conv
//     reads at (o+4(rr&3))&15 -> still 16 distinct banks. Row-256 guard
//     unaffected (256&3=0 -> column o, zeroed).
// (2) scan: 1 wave/SIMD structural, u reads ~900cy HBM, old prefetch
//     covered ~150cy. Now 2x4-t buffers issued ahead (~8-12t depth).
// (3) scan<true>: 64 blocks -> 256 blocks of 64 threads (all CUs).
// Gates: WRITE_SIZE exactly 131072 KB; BANK_CONFLICT < 1.5M.
// Numerics byte-identical (absmax 0.0): FIR order, scan order, digit
// planes, recombine untouched -- placement/scheduling only.

#define TT     256
#define KLEN   62
#define THETA  10.0

typedef int v4i __attribute__((ext_vector_type(4)));

// ===================== expand x -> i8 B-matrix (layer 1) ====================
// x: [32][1024][256] f32 {0,1}; bexp: [b][g=i/16][t][m=i%16] i8 {0,1}
__global__ __launch_bounds__(256)
void expand_x(const float* __restrict__ x, signed char* __restrict__ bexp)
{
    const int b = blockIdx.x;
    const int g = blockIdx.y;             // 64 groups of 16 inputs
    const int t = threadIdx.x;
    const float* xp = x + ((size_t)b*1024 + g*16)*TT + t;
    uint32_t uu[4];
    #pragma unroll
    for (int j = 0; j < 4; ++j) {
        uint32_t w = 0;
        #pragma unroll
        for (int m = 0; m < 4; ++m)
            w |= (xp[(size_t)(j*4 + m)*TT] >= 0.5f) ? (1u << (8*m)) : 0u;
        uu[j] = w;
    }
    *(uint4*)(bexp + (((size_t)b*64 + g)*256 + t)*16) = *(const uint4*)uu;
}

// ====================== weight -> int8 digit planes (swizzled) ==============
// planes: [oblk][s(I/64)][p(5)][lane(64)][16 B] -- MFMA A-frag register order:
// lane = quad*16+col holds digits of w[oblk*16+col][s*64 + quad*16 + 0..15].
__global__ __launch_bounds__(256)
void decompose_i8(const float* __restrict__ w, signed char* __restrict__ planes,
                  int I, int total)
{
    const int f = blockIdx.x * 256 + threadIdx.x;
    if (f >= total) return;
    const int NS = I / 64;
    const int per_oblk = NS * 5120;
    int rem  = f;
    const int oblk = rem / per_oblk;  rem -= oblk * per_oblk;
    const int s    = rem / 5120;      rem -= s * 5120;
    const int p    = rem >> 10;
    const int l    = (rem & 1023) >> 4;
    const int j    = rem & 15;
    const int quad = l >> 4, col = l & 15;
    const float wv = w[(size_t)(oblk*16 + col) * I + s*64 + quad*16 + j];
    long long v = llrint((double)wv * 274877906944.0);   // w * 2^38, exact int
    int d = 0;
    for (int q = 0; q <= p; ++q) {                       // balanced base-256
        d = (int)((v + 128) & 255) - 128;
        v = (v - d) >> 8;
    }
    planes[f] = (signed char)d;
}

// ====================== fused gemm+conv kernel ==============================
// grid (B, O/16): b fastest (A-planes L2-hot). Phase 1: two-pass acc[5][2]
// i8 MFMA (R22 loop -- R23 prefetch reverted as proven-null) -> exact fp64
// recombine into a_lds at SWIZZLED column (j + 4(t&3))&15 (conflict-free
// writes). Barrier. Phase 2: 61-tap FIR reading the swizzled columns.
// Max live ~84 VGPR < 128 cap -> 4 waves/SIMD.
template<int I>
__global__ __launch_bounds__(256) __attribute__((amdgpu_num_vgpr(128)))
void fused_gc(const signed char* __restrict__ bexp,    // [b][I/16][256][16]
              const signed char* __restrict__ planes,  // swizzled A planes
              double*            __restrict__ u,       // [B][256][OS]
              int OS)
{
    constexpr int NS = I / 64;
    __shared__ double a_lds[257 * 17];                   // 34.95 KB (row 256 = 0)
    __shared__ double srmE[68];

    const int tid  = threadIdx.x;
    const int lane = tid & 63;
    const int wvu  = tid >> 6;
    const int quad = lane >> 4;
    const int col  = lane & 15;
    const int b    = blockIdx.x;
    const int oblk = blockIdx.y;
    const int o0   = oblk * 16;
    const int tw   = wvu * 64;

    if (tid < 68) {
        const int k = tid - 2;
        double v = 0.0;
        if (k >= 1 && k <= 61) {
            double wv = (double)k / 8.0 * exp(1.0 - (double)k / 8.0);
            v = (double)(float)wv;     // fp32-rounded tap, widened (R1-R23)
        }
        srmE[tid] = v;
    }

    // ---------------- phase 1: gemm (R22-proven loop) -----------------------
    const signed char* Apg = planes + (size_t)oblk * NS * 5120 + lane * 16;
    const double inv = 1.0 / 274877906944.0;             // 2^-38

    #pragma unroll 1
    for (int half = 0; half < 2; ++half) {
        const signed char* Bx = bexp +
            (((size_t)b*(I/16) + quad)*256 + tw + half*32 + col)*16;

        v4i acc[5][2];
        #pragma unroll
        for (int p = 0; p < 5; ++p)
            #pragma unroll
            for (int nt = 0; nt < 2; ++nt)
                acc[p][nt] = (v4i){0, 0, 0, 0};

        #pragma unroll 1
        for (int s = 0; s < NS; ++s) {
            v4i af[5];
            #pragma unroll
            for (int p = 0; p < 5; ++p)
                af[p] = *(const v4i*)(const void*)(Apg + (size_t)s * 5120 + p * 1024);
            v4i bf[2];
            #pragma unroll
            for (int nt = 0; nt < 2; ++nt)
                bf[nt] = *(const v4i*)(const void*)(Bx + (size_t)s * 16384 + nt * 256);

            #pragma unroll
            for (int nt = 0; nt < 2; ++nt)
                #pragma unroll
                for (int p = 0; p < 5; ++p)
                    acc[p][nt] = __builtin_amdgcn_mfma_i32_16x16x64_i8(
                                     af[p], bf[nt], acc[p][nt], 0, 0, 0);
        }

        // recombine: exact fp64 a into LDS at swizzled column ----------------
        #pragma unroll
        for (int nt = 0; nt < 2; ++nt) {
            const int t = tw + half*32 + nt*16 + col;
            const int cb = quad*4 + ((t & 3) << 2);      // wrap-free base
            #pragma unroll
            for (int r = 0; r < 4; ++r) {
                double v =            (double)acc[4][nt][r];
                v = v * 256.0 + (double)acc[3][nt][r];
                v = v * 256.0 + (double)acc[2][nt][r];
                v = v * 256.0 + (double)acc[1][nt][r];
                v = v * 256.0 + (double)acc[0][nt][r];
                a_lds[t * 17 + ((cb + r) & 15)] = v * inv;
            }
        }
    }

    if (tid < 17) a_lds[256 * 17 + tid] = 0.0;           // zero-guard row
    __syncthreads();                                     // the only barrier

    // ---------------- phase 2: conv (swizzled-column reads) -----------------
    const int o    = tid & 15;
    const int tgrp = tid >> 4;                           // 0..15
    #pragma unroll 1
    for (int pass = 0; pass < 4; ++pass) {
        const int T0b = pass * 64 + tgrp * 4;
        double u0 = 0, u1 = 0, u2 = 0, u3 = 0;
        double w1 = srmE[64], w2 = srmE[65], w3 = srmE[66];   // zero pads
        for (int d = 0; d < 64; d += 4) {
            const int row = T0b - 61 + d;
            const int rr0 = (row + 0 < 0) ? 256 : row + 0;
            const int rr1 = (row + 1 < 0) ? 256 : row + 1;
            const int rr2 = (row + 2 < 0) ? 256 : row + 2;
            const int rr3 = (row + 3 < 0) ? 256 : row + 3;
            const double av0 = a_lds[rr0 * 17 + ((o + ((rr0 & 3) << 2)) & 15)];
            const double av1 = a_lds[rr1 * 17 + ((o + ((rr1 & 3) << 2)) & 15)];
            const double av2 = a_lds[rr2 * 17 + ((o + ((rr2 & 3) << 2)) & 15)];
            const double av3 = a_lds[rr3 * 17 + ((o + ((rr3 & 3) << 2)) & 15)];
            const double n0 = srmE[63 - d], n1 = srmE[62 - d];
            const double n2 = srmE[61 - d], n3 = srmE[60 - d];
            u0 = fma(n0, av0, u0); u1 = fma(w1, av0, u1); u2 = fma(w2, av0, u2); u3 = fma(w3, av0, u3);
            u0 = fma(n1, av1, u0); u1 = fma(n0, av1, u1); u2 = fma(w1, av1, u2); u3 = fma(w2, av1, u3);
            u0 = fma(n2, av2, u0); u1 = fma(n1, av2, u1); u2 = fma(n0, av2, u2); u3 = fma(w1, av2, u3);
            u0 = fma(n3, av3, u0); u1 = fma(n2, av3, u1); u2 = fma(n1, av3, u2); u3 = fma(n0, av3, u3);
            w1 = n3; w2 = n2; w3 = n1;
        }
        double* up = u + ((size_t)b * 256 + T0b) * OS + o0 + o;
        up[0]              = u0;
        up[(size_t)OS]     = u1;
        up[(size_t)OS * 2] = u2;
        up[(size_t)OS * 3] = u3;
    }
}

// ========================== scan (R8/R10-verified core) =====================
// lane = neuron; 256 sequential steps; refractory via 61-bit history mask.
// Prefetch: two 4-t buffers issued ahead of processing (~8-12t depth, covers
// ~2.5x more of the ~900cy HBM latency at 1 wave/SIMD).
// FINAL=false: 256-thread blocks; ballots -> expanded i8 bexp_out.
// FINAL=true:  64-thread blocks, grid (8,32) -> all CUs; f32 out[b][o][t].
template<bool FINAL>
__global__ void scan_spikes(const double* __restrict__ u,
                            signed char* __restrict__ bexp_out,
                            float* __restrict__ f32_out, int OS)
{
    __shared__ double   ref64[KLEN];
    __shared__ uint32_t blds[8][256];   // 8 KB ballot staging
    const int tid = threadIdx.x;
    if (tid < KLEN) {
        double v = (double)tid / 8.0 * exp(1.0 - (double)tid / 8.0);
        ref64[tid] = (double)(float)(-20.0 * v);
    }
    __syncthreads();

    const int nthr  = FINAL ? 64 : 256;
    const int b     = blockIdx.y;
    const int obase = blockIdx.x * nthr;
    const int o     = obase + tid;
    const int lane  = tid & 63;
    const int wv    = tid >> 6;
    const double* up = u + (size_t)b * TT * OS + o;

    uint64_t mask = 0;
    // prefetch pipeline: cur (t0..t0+3), nx1 (t0+4..7) live; nx2 issued in-loop
    double c0 = up[0], c1 = up[OS], c2 = up[2*(size_t)OS], c3 = up[3*(size_t)OS];
    double d0 = up[4*(size_t)OS], d1 = up[5*(size_t)OS],
           d2 = up[6*(size_t)OS], d3 = up[7*(size_t)OS];
    for (int t0 = 0; t0 < TT; t0 += 8) {
        double e0 = 0, e1 = 0, e2 = 0, e3 = 0;
        double f0 = 0, f1 = 0, f2 = 0, f3 = 0;
        if (t0 + 8 < TT) {
            const double* p1 = up + (size_t)(t0 + 8) * OS;
            e0 = p1[0]; e1 = p1[OS]; e2 = p1[2*(size_t)OS]; e3 = p1[3*(size_t)OS];
            const double* p2 = up + (size_t)(t0 + 12) * OS;
            f0 = p2[0]; f1 = p2[OS]; f2 = p2[2*(size_t)OS]; f3 = p2[3*(size_t)OS];
        }
        #pragma unroll
        for (int g = 0; g < 2; ++g) {
            #pragma unroll
            for (int q = 0; q < 4; ++q) {
                const double uv =
                    (g == 0) ? ((q == 0) ? c0 : (q == 1) ? c1 : (q == 2) ? c2 : c3)
                             : ((q == 0) ? d0 : (q == 1) ? d1 : (q == 2) ? d2 : d3);
                uint64_t m = mask;
                double r0 = 0.0, r1 = 0.0;
                while (m) {
                    int p = __builtin_ctzll(m); m &= m - 1;
                    r0 += ref64[p + 1];
                    if (m) { int pq = __builtin_ctzll(m); m &= m - 1; r1 += ref64[pq + 1]; }
                }
                const bool s = (uv + (r0 + r1)) >= THETA;
                const uint64_t bal = __ballot(s);
                if (lane == 0) {
                    blds[wv * 2 + 0][t0 + g*4 + q] = (uint32_t)bal;
                    blds[wv * 2 + 1][t0 + g*4 + q] = (uint32_t)(bal >> 32);
                }
                mask = ((mask << 1) | (s ? 1ull : 0ull)) & ((1ull << 61) - 1ull);
            }
        }
        c0 = e0; c1 = e1; c2 = e2; c3 = e3;
        d0 = f0; d1 = f1; d2 = f2; d3 = f3;
    }
    __syncthreads();

    if (!FINAL) {
        // expand ballots to i8 B-matrix: entry g = obase/16 + gl, byte m =
        // bit ((gl&1)*16 + m) of word blds[gl>>1][t]  (i = g*16 + m)
        const int gbase = obase >> 4;
        for (int e = tid; e < 16 * 256; e += 256) {
            const int gl = e >> 8, t = e & 255;
            const uint32_t w = blds[gl >> 1][t];
            const uint32_t h = (w >> ((gl & 1) * 16)) & 0xFFFFu;
            uint32_t uu[4];
            #pragma unroll
            for (int j = 0; j < 4; ++j)
                uu[j] = (((h >> (4*j)) & 0xFu) * 0x00204081u) & 0x01010101u;
            *(uint4*)(bexp_out + (((size_t)b*128 + gbase + gl)*256 + t)*16) =
                *(const uint4*)uu;
        }
    } else {
        // 64-thread blocks: 64 neurons x 256 t, coalesced 256B rows
        for (int e = tid; e < 64 * 256; e += 64) {
            const int ol = e >> 8, tq = e & 255;
            const uint32_t w = blds[ol >> 5][tq];
            f32_out[((size_t)b * 512 + obase + ol) * TT + tq] =
                (float)((w >> (ol & 31)) & 1u);
        }
    }
}

// ================================ launcher ==================================
extern "C" void kernel_launch(void* const* d_in, const int* in_sizes, int n_in,
                              void* d_out, int out_size, void* d_ws, size_t ws_size,
                              hipStream_t stream)
{
    const float* x  = (const float*)d_in[0];   // [32][1024][256]
    const float* w1 = (const float*)d_in[1];   // [2048][1024]
    const float* w2 = (const float*)d_in[2];   // [512][2048]
    float* out = (float*)d_out;                // [32][512][256]

    char* ws = (char*)d_ws;
    // liveness-based layout (Bexp2 aliases dead P1/Bexp1): total ~158 MB
    signed char* P2    = (signed char*)ws;                      // 5.25 MB
    size_t roff = (size_t)32 * 32 * 5120;                       // 5242880
    signed char* P1    = (signed char*)(ws + roff);             // 10.5 MB
    signed char* Bexp1 = (signed char*)(ws + roff + (size_t)128*16*5120); // 8 MB
    signed char* Bexp2 = (signed char*)(ws + roff);             // 16 MB (alias)
    size_t uoff = roff + (size_t)128*16*5120 + (size_t)32*64*256*16; // 24117248
    double* uBuf = (double*)(ws + uoff);                        // 134 MB

    expand_x<<<dim3(32, 64), 256, 0, stream>>>(x, Bexp1);
    decompose_i8<<<dim3((10485760 + 255)/256), 256, 0, stream>>>(w1, P1, 1024, 10485760);
    decompose_i8<<<dim3((5242880  + 255)/256), 256, 0, stream>>>(w2, P2, 2048, 5242880);

    // layer 1: 1024 -> 2048  (fused gemm+conv: u written directly)
    fused_gc<1024><<<dim3(32, 128), 256, 0, stream>>>(Bexp1, P1, uBuf, 2048);
    scan_spikes<false><<<dim3(8, 32), 256, 0, stream>>>(uBuf, Bexp2, nullptr, 2048);
    // layer 2: 2048 -> 512
    fused_gc<2048><<<dim3(32, 32), 256, 0, stream>>>(Bexp2, P2, uBuf, 512);
    scan_spikes<true><<<dim3(8, 32), 64, 0, stream>>>(uBuf, nullptr, out, 512);
}

// Round 13
// 472.163 us; speedup vs baseline: 1.2284x; 1.1390x over previous
//
#include <hip/hip_runtime.h>
#include <math.h>
#include <stdint.h>

// SLAYER 2-layer SNN. Round 25: byte-table refractory in the scans.
//   expand_x -> decompose_i8 x2 ->
//   fused_gc<1024> -> scan<BITS->Bexp2> -> fused_gc<2048> -> scan<F32>.
// R24 post-mortem: 537.8us best, but BANK_CONFLICT rose (7.18->7.44M) --
// swizzle theory WRONG: b64 wave access = 128 bank-requests/32 banks =
// 4/bank is the hardware MINIMUM; both write+read were already at floor.
// That counter is unavoidable aliasing; lever closed. The -36us came from
// the scan tweaks. Budget: fused 192+~90, prep ~25 -> ~230us in the SCANS
// (largest chunk, hidden below top-5). Scan inner loop = per-t ctz-walk of
// the 61-bit mask with DEPENDENT ref64[p+1] LDS reads: 10-25 serial
// iterations x ~70-100cy at 1 wave/SIMD (structural).
// R25: tbl[j][byte] = sum of ref taps for that byte's bits (8x256 dbl,
// 16 KB LDS, built once); per-t refractory = 8 INDEPENDENT reads + 7 adds
// -> one latency window. fp64 reorder of identical fp32-rounded taps:
// current code already reorders vs f32 reference and holds absmax 0.0;
// reorder noise ~1e-15 << decision margins. fused_gc/prep untouched.
// Gate: absmax 0.0; fused counters identical.

#define TT     256
#define KLEN   62
#define THETA  10.0

typedef int v4i __attribute__((ext_vector_type(4)));

// ===================== expand x -> i8 B-matrix (layer 1) ====================
// x: [32][1024][256] f32 {0,1}; bexp: [b][g=i/16][t][m=i%16] i8 {0,1}
__global__ __launch_bounds__(256)
void expand_x(const float* __restrict__ x, signed char* __restrict__ bexp)
{
    const int b = blockIdx.x;
    const int g = blockIdx.y;             // 64 groups of 16 inputs
    const int t = threadIdx.x;
    const float* xp = x + ((size_t)b*1024 + g*16)*TT + t;
    uint32_t uu[4];
    #pragma unroll
    for (int j = 0; j < 4; ++j) {
        uint32_t w = 0;
        #pragma unroll
        for (int m = 0; m < 4; ++m)
            w |= (xp[(size_t)(j*4 + m)*TT] >= 0.5f) ? (1u << (8*m)) : 0u;
        uu[j] = w;
    }
    *(uint4*)(bexp + (((size_t)b*64 + g)*256 + t)*16) = *(const uint4*)uu;
}

// ====================== weight -> int8 digit planes (swizzled) ==============
// planes: [oblk][s(I/64)][p(5)][lane(64)][16 B] -- MFMA A-frag register order:
// lane = quad*16+col holds digits of w[oblk*16+col][s*64 + quad*16 + 0..15].
__global__ __launch_bounds__(256)
void decompose_i8(const float* __restrict__ w, signed char* __restrict__ planes,
                  int I, int total)
{
    const int f = blockIdx.x * 256 + threadIdx.x;
    if (f >= total) return;
    const int NS = I / 64;
    const int per_oblk = NS * 5120;
    int rem  = f;
    const int oblk = rem / per_oblk;  rem -= oblk * per_oblk;
    const int s    = rem / 5120;      rem -= s * 5120;
    const int p    = rem >> 10;
    const int l    = (rem & 1023) >> 4;
    const int j    = rem & 15;
    const int quad = l >> 4, col = l & 15;
    const float wv = w[(size_t)(oblk*16 + col) * I + s*64 + quad*16 + j];
    long long v = llrint((double)wv * 274877906944.0);   // w * 2^38, exact int
    int d = 0;
    for (int q = 0; q <= p; ++q) {                       // balanced base-256
        d = (int)((v + 128) & 255) - 128;
        v = (v - d) >> 8;
    }
    planes[f] = (signed char)d;
}

// ====================== fused gemm+conv kernel (R24-proven) =================
// grid (B, O/16): b fastest (A-planes L2-hot). Phase 1: two-pass acc[5][2]
// i8 MFMA -> exact fp64 recombine into a_lds (swizzled column). Barrier.
// Phase 2: 61-tap FIR reading swizzled columns -> u. 4 waves/SIMD.
template<int I>
__global__ __launch_bounds__(256) __attribute__((amdgpu_num_vgpr(128)))
void fused_gc(const signed char* __restrict__ bexp,    // [b][I/16][256][16]
              const signed char* __restrict__ planes,  // swizzled A planes
              double*            __restrict__ u,       // [B][256][OS]
              int OS)
{
    constexpr int NS = I / 64;
    __shared__ double a_lds[257 * 17];                   // 34.95 KB (row 256 = 0)
    __shared__ double srmE[68];

    const int tid  = threadIdx.x;
    const int lane = tid & 63;
    const int wvu  = tid >> 6;
    const int quad = lane >> 4;
    const int col  = lane & 15;
    const int b    = blockIdx.x;
    const int oblk = blockIdx.y;
    const int o0   = oblk * 16;
    const int tw   = wvu * 64;

    if (tid < 68) {
        const int k = tid - 2;
        double v = 0.0;
        if (k >= 1 && k <= 61) {
            double wv = (double)k / 8.0 * exp(1.0 - (double)k / 8.0);
            v = (double)(float)wv;     // fp32-rounded tap, widened (R1-R24)
        }
        srmE[tid] = v;
    }

    // ---------------- phase 1: gemm (R22-proven loop) -----------------------
    const signed char* Apg = planes + (size_t)oblk * NS * 5120 + lane * 16;
    const double inv = 1.0 / 274877906944.0;             // 2^-38

    #pragma unroll 1
    for (int half = 0; half < 2; ++half) {
        const signed char* Bx = bexp +
            (((size_t)b*(I/16) + quad)*256 + tw + half*32 + col)*16;

        v4i acc[5][2];
        #pragma unroll
        for (int p = 0; p < 5; ++p)
            #pragma unroll
            for (int nt = 0; nt < 2; ++nt)
                acc[p][nt] = (v4i){0, 0, 0, 0};

        #pragma unroll 1
        for (int s = 0; s < NS; ++s) {
            v4i af[5];
            #pragma unroll
            for (int p = 0; p < 5; ++p)
                af[p] = *(const v4i*)(const void*)(Apg + (size_t)s * 5120 + p * 1024);
            v4i bf[2];
            #pragma unroll
            for (int nt = 0; nt < 2; ++nt)
                bf[nt] = *(const v4i*)(const void*)(Bx + (size_t)s * 16384 + nt * 256);

            #pragma unroll
            for (int nt = 0; nt < 2; ++nt)
                #pragma unroll
                for (int p = 0; p < 5; ++p)
                    acc[p][nt] = __builtin_amdgcn_mfma_i32_16x16x64_i8(
                                     af[p], bf[nt], acc[p][nt], 0, 0, 0);
        }

        // recombine: exact fp64 a into LDS at swizzled column ----------------
        #pragma unroll
        for (int nt = 0; nt < 2; ++nt) {
            const int t = tw + half*32 + nt*16 + col;
            const int cb = quad*4 + ((t & 3) << 2);      // wrap-free base
            #pragma unroll
            for (int r = 0; r < 4; ++r) {
                double v =            (double)acc[4][nt][r];
                v = v * 256.0 + (double)acc[3][nt][r];
                v = v * 256.0 + (double)acc[2][nt][r];
                v = v * 256.0 + (double)acc[1][nt][r];
                v = v * 256.0 + (double)acc[0][nt][r];
                a_lds[t * 17 + ((cb + r) & 15)] = v * inv;
            }
        }
    }

    if (tid < 17) a_lds[256 * 17 + tid] = 0.0;           // zero-guard row
    __syncthreads();                                     // the only barrier

    // ---------------- phase 2: conv (swizzled-column reads) -----------------
    const int o    = tid & 15;
    const int tgrp = tid >> 4;                           // 0..15
    #pragma unroll 1
    for (int pass = 0; pass < 4; ++pass) {
        const int T0b = pass * 64 + tgrp * 4;
        double u0 = 0, u1 = 0, u2 = 0, u3 = 0;
        double w1 = srmE[64], w2 = srmE[65], w3 = srmE[66];   // zero pads
        for (int d = 0; d < 64; d += 4) {
            const int row = T0b - 61 + d;
            const int rr0 = (row + 0 < 0) ? 256 : row + 0;
            const int rr1 = (row + 1 < 0) ? 256 : row + 1;
            const int rr2 = (row + 2 < 0) ? 256 : row + 2;
            const int rr3 = (row + 3 < 0) ? 256 : row + 3;
            const double av0 = a_lds[rr0 * 17 + ((o + ((rr0 & 3) << 2)) & 15)];
            const double av1 = a_lds[rr1 * 17 + ((o + ((rr1 & 3) << 2)) & 15)];
            const double av2 = a_lds[rr2 * 17 + ((o + ((rr2 & 3) << 2)) & 15)];
            const double av3 = a_lds[rr3 * 17 + ((o + ((rr3 & 3) << 2)) & 15)];
            const double n0 = srmE[63 - d], n1 = srmE[62 - d];
            const double n2 = srmE[61 - d], n3 = srmE[60 - d];
            u0 = fma(n0, av0, u0); u1 = fma(w1, av0, u1); u2 = fma(w2, av0, u2); u3 = fma(w3, av0, u3);
            u0 = fma(n1, av1, u0); u1 = fma(n0, av1, u1); u2 = fma(w1, av1, u2); u3 = fma(w2, av1, u3);
            u0 = fma(n2, av2, u0); u1 = fma(n1, av2, u1); u2 = fma(n0, av2, u2); u3 = fma(w1, av2, u3);
            u0 = fma(n3, av3, u0); u1 = fma(n2, av3, u1); u2 = fma(n1, av3, u2); u3 = fma(n0, av3, u3);
            w1 = n3; w2 = n2; w3 = n1;
        }
        double* up = u + ((size_t)b * 256 + T0b) * OS + o0 + o;
        up[0]              = u0;
        up[(size_t)OS]     = u1;
        up[(size_t)OS * 2] = u2;
        up[(size_t)OS * 3] = u3;
    }
}

// ========================== scan (byte-table refractory) ====================
// lane = neuron; 256 sequential steps. Refractory via 8 independent LDS
// table lookups (tbl[j][byte] = sum of taps for that byte of the 61-bit
// history mask) instead of the serial ctz/LDS-dependent walk.
// FINAL=false: 256-thread blocks; ballots -> expanded i8 bexp_out.
// FINAL=true:  64-thread blocks, grid (8,32) -> all CUs; f32 out[b][o][t].
template<bool FINAL>
__global__ void scan_spikes(const double* __restrict__ u,
                            signed char* __restrict__ bexp_out,
                            float* __restrict__ f32_out, int OS)
{
    __shared__ double   ref64[KLEN];
    __shared__ double   tbl[8 * 256];   // 16 KB byte-sum tables
    __shared__ uint32_t blds[8][256];   // 8 KB ballot staging
    const int tid  = threadIdx.x;
    const int nthr = FINAL ? 64 : 256;

    if (tid < KLEN) {
        double v = (double)tid / 8.0 * exp(1.0 - (double)tid / 8.0);
        ref64[tid] = (double)(float)(-20.0 * v);
    }
    __syncthreads();
    for (int e = tid; e < 2048; e += nthr) {
        const int j = e >> 8, v = e & 255;
        double s = 0.0;
        #pragma unroll
        for (int i = 0; i < 8; ++i) {
            const int k = j * 8 + i + 1;
            if (k <= 61)
                s += ((v >> i) & 1) ? ref64[k] : 0.0;
        }
        tbl[e] = s;
    }
    __syncthreads();

    const int b     = blockIdx.y;
    const int obase = blockIdx.x * nthr;
    const int o     = obase + tid;
    const int lane  = tid & 63;
    const int wv    = tid >> 6;
    const double* up = u + (size_t)b * TT * OS + o;

    uint64_t mask = 0;
    // prefetch pipeline: 8 u-values in flight (R24-proven)
    double c0 = up[0], c1 = up[OS], c2 = up[2*(size_t)OS], c3 = up[3*(size_t)OS];
    double d0 = up[4*(size_t)OS], d1 = up[5*(size_t)OS],
           d2 = up[6*(size_t)OS], d3 = up[7*(size_t)OS];
    for (int t0 = 0; t0 < TT; t0 += 8) {
        double e0 = 0, e1 = 0, e2 = 0, e3 = 0;
        double f0 = 0, f1 = 0, f2 = 0, f3 = 0;
        if (t0 + 8 < TT) {
            const double* p1 = up + (size_t)(t0 + 8) * OS;
            e0 = p1[0]; e1 = p1[OS]; e2 = p1[2*(size_t)OS]; e3 = p1[3*(size_t)OS];
            const double* p2 = up + (size_t)(t0 + 12) * OS;
            f0 = p2[0]; f1 = p2[OS]; f2 = p2[2*(size_t)OS]; f3 = p2[3*(size_t)OS];
        }
        #pragma unroll
        for (int g = 0; g < 2; ++g) {
            #pragma unroll
            for (int q = 0; q < 4; ++q) {
                const double uv =
                    (g == 0) ? ((q == 0) ? c0 : (q == 1) ? c1 : (q == 2) ? c2 : c3)
                             : ((q == 0) ? d0 : (q == 1) ? d1 : (q == 2) ? d2 : d3);
                const uint64_t m = mask;
                const double ra = tbl[        (int)( m        & 255)]
                                + tbl[256   + (int)((m >>  8) & 255)];
                const double rb = tbl[512   + (int)((m >> 16) & 255)]
                                + tbl[768   + (int)((m >> 24) & 255)];
                const double rc = tbl[1024  + (int)((m >> 32) & 255)]
                                + tbl[1280  + (int)((m >> 40) & 255)];
                const double rd = tbl[1536  + (int)((m >> 48) & 255)]
                                + tbl[1792  + (int)((m >> 56) & 255)];
                const double r  = (ra + rb) + (rc + rd);
                const bool s = (uv + r) >= THETA;
                const uint64_t bal = __ballot(s);
                if (lane == 0) {
                    blds[wv * 2 + 0][t0 + g*4 + q] = (uint32_t)bal;
                    blds[wv * 2 + 1][t0 + g*4 + q] = (uint32_t)(bal >> 32);
                }
                mask = ((mask << 1) | (s ? 1ull : 0ull)) & ((1ull << 61) - 1ull);
            }
        }
        c0 = e0; c1 = e1; c2 = e2; c3 = e3;
        d0 = f0; d1 = f1; d2 = f2; d3 = f3;
    }
    __syncthreads();

    if (!FINAL) {
        // expand ballots to i8 B-matrix: entry g = obase/16 + gl, byte m =
        // bit ((gl&1)*16 + m) of word blds[gl>>1][t]  (i = g*16 + m)
        const int gbase = obase >> 4;
        for (int e = tid; e < 16 * 256; e += 256) {
            const int gl = e >> 8, t = e & 255;
            const uint32_t w = blds[gl >> 1][t];
            const uint32_t h = (w >> ((gl & 1) * 16)) & 0xFFFFu;
            uint32_t uu[4];
            #pragma unroll
            for (int j = 0; j < 4; ++j)
                uu[j] = (((h >> (4*j)) & 0xFu) * 0x00204081u) & 0x01010101u;
            *(uint4*)(bexp_out + (((size_t)b*128 + gbase + gl)*256 + t)*16) =
                *(const uint4*)uu;
        }
    } else {
        // 64-thread blocks: 64 neurons x 256 t, coalesced 256B rows
        for (int e = tid; e < 64 * 256; e += 64) {
            const int ol = e >> 8, tq = e & 255;
            const uint32_t w = blds[ol >> 5][tq];
            f32_out[((size_t)b * 512 + obase + ol) * TT + tq] =
                (float)((w >> (ol & 31)) & 1u);
        }
    }
}

// ================================ launcher ==================================
extern "C" void kernel_launch(void* const* d_in, const int* in_sizes, int n_in,
                              void* d_out, int out_size, void* d_ws, size_t ws_size,
                              hipStream_t stream)
{
    const float* x  = (const float*)d_in[0];   // [32][1024][256]
    const float* w1 = (const float*)d_in[1];   // [2048][1024]
    const float* w2 = (const float*)d_in[2];   // [512][2048]
    float* out = (float*)d_out;                // [32][512][256]

    char* ws = (char*)d_ws;
    // liveness-based layout (Bexp2 aliases dead P1/Bexp1): total ~158 MB
    signed char* P2    = (signed char*)ws;                      // 5.25 MB
    size_t roff = (size_t)32 * 32 * 5120;                       // 5242880
    signed char* P1    = (signed char*)(ws + roff);             // 10.5 MB
    signed char* Bexp1 = (signed char*)(ws + roff + (size_t)128*16*5120); // 8 MB
    signed char* Bexp2 = (signed char*)(ws + roff);             // 16 MB (alias)
    size_t uoff = roff + (size_t)128*16*5120 + (size_t)32*64*256*16; // 24117248
    double* uBuf = (double*)(ws + uoff);                        // 134 MB

    expand_x<<<dim3(32, 64), 256, 0, stream>>>(x, Bexp1);
    decompose_i8<<<dim3((10485760 + 255)/256), 256, 0, stream>>>(w1, P1, 1024, 10485760);
    decompose_i8<<<dim3((5242880  + 255)/256), 256, 0, stream>>>(w2, P2, 2048, 5242880);

    // layer 1: 1024 -> 2048  (fused gemm+conv: u written directly)
    fused_gc<1024><<<dim3(32, 128), 256, 0, stream>>>(Bexp1, P1, uBuf, 2048);
    scan_spikes<false><<<dim3(8, 32), 256, 0, stream>>>(uBuf, Bexp2, nullptr, 2048);
    // layer 2: 2048 -> 512
    fused_gc<2048><<<dim3(32, 32), 256, 0, stream>>>(Bexp2, P2, uBuf, 512);
    scan_spikes<true><<<dim3(8, 32), 64, 0, stream>>>(uBuf, nullptr, out, 512);
}

// Round 14
// 429.295 us; speedup vs baseline: 1.3511x; 1.0999x over previous
//
#include <hip/hip_runtime.h>
#include <math.h>
#include <stdint.h>

// SLAYER 2-layer SNN. Round 26: merged single-pass gemm + 16-t scan prefetch.
//   expand_x -> decompose_i8 x2 ->
//   fused_gc<1024> -> scan<BITS->Bexp2> -> fused_gc<2048> -> scan<F32>.
// R25 post-mortem: byte-table refractory -65.6us (472.2 best). Budget:
// fused<1024> 190 + fused<2048> ~88 + scans ~160 + prep ~30.
// R26a: gemm merge. MfmaUtil 19.7% x 190us = 37us pipe-time ~= the 44us
// MFMA floor -> waste is load issue: two-pass loads 5af+2bf per 10 MFMA,
// and af (5KB A-slab) is loaded redundantly. At measured VGPR=52 the
// two-pass split (a 196-VGPR-era fix) is obsolete: merged acc[5][4]
// (R17 indexing, nt=half*2+nt2 verified identical addresses) is ~115 live
// < 128 cap and HALVES af loads (loads/MFMA 0.7 -> 0.45). Per-chain MFMA
// order still s-ascending -> bit-identical i32.
// R26b: scan 3-stage prefetch (hold 16 t, issue +16 ahead) covers the
// ~900cy HBM latency at 1 wave/SIMD (R24's depth-8 covered ~half).
// Gates: WRITE_SIZE exactly 131072 KB (spill); absmax 0.0.

#define TT     256
#define KLEN   62
#define THETA  10.0

typedef int v4i __attribute__((ext_vector_type(4)));

// ===================== expand x -> i8 B-matrix (layer 1) ====================
// x: [32][1024][256] f32 {0,1}; bexp: [b][g=i/16][t][m=i%16] i8 {0,1}
__global__ __launch_bounds__(256)
void expand_x(const float* __restrict__ x, signed char* __restrict__ bexp)
{
    const int b = blockIdx.x;
    const int g = blockIdx.y;             // 64 groups of 16 inputs
    const int t = threadIdx.x;
    const float* xp = x + ((size_t)b*1024 + g*16)*TT + t;
    uint32_t uu[4];
    #pragma unroll
    for (int j = 0; j < 4; ++j) {
        uint32_t w = 0;
        #pragma unroll
        for (int m = 0; m < 4; ++m)
            w |= (xp[(size_t)(j*4 + m)*TT] >= 0.5f) ? (1u << (8*m)) : 0u;
        uu[j] = w;
    }
    *(uint4*)(bexp + (((size_t)b*64 + g)*256 + t)*16) = *(const uint4*)uu;
}

// ====================== weight -> int8 digit planes (swizzled) ==============
// planes: [oblk][s(I/64)][p(5)][lane(64)][16 B] -- MFMA A-frag register order:
// lane = quad*16+col holds digits of w[oblk*16+col][s*64 + quad*16 + 0..15].
__global__ __launch_bounds__(256)
void decompose_i8(const float* __restrict__ w, signed char* __restrict__ planes,
                  int I, int total)
{
    const int f = blockIdx.x * 256 + threadIdx.x;
    if (f >= total) return;
    const int NS = I / 64;
    const int per_oblk = NS * 5120;
    int rem  = f;
    const int oblk = rem / per_oblk;  rem -= oblk * per_oblk;
    const int s    = rem / 5120;      rem -= s * 5120;
    const int p    = rem >> 10;
    const int l    = (rem & 1023) >> 4;
    const int j    = rem & 15;
    const int quad = l >> 4, col = l & 15;
    const float wv = w[(size_t)(oblk*16 + col) * I + s*64 + quad*16 + j];
    long long v = llrint((double)wv * 274877906944.0);   // w * 2^38, exact int
    int d = 0;
    for (int q = 0; q <= p; ++q) {                       // balanced base-256
        d = (int)((v + 128) & 255) - 128;
        v = (v - d) >> 8;
    }
    planes[f] = (signed char)d;
}

// ====================== fused gemm+conv kernel ==============================
// grid (B, O/16): b fastest (A-planes L2-hot). Phase 1: SINGLE-PASS
// acc[5][4] i8 MFMA (merged halves -- af loads halved; R17-verified B
// indexing) -> exact fp64 recombine into a_lds (swizzled column). Barrier.
// Phase 2: 61-tap FIR reading swizzled columns -> u. Est live ~115 < 128.
template<int I>
__global__ __launch_bounds__(256) __attribute__((amdgpu_num_vgpr(128)))
void fused_gc(const signed char* __restrict__ bexp,    // [b][I/16][256][16]
              const signed char* __restrict__ planes,  // swizzled A planes
              double*            __restrict__ u,       // [B][256][OS]
              int OS)
{
    constexpr int NS = I / 64;
    __shared__ double a_lds[257 * 17];                   // 34.95 KB (row 256 = 0)
    __shared__ double srmE[68];

    const int tid  = threadIdx.x;
    const int lane = tid & 63;
    const int wvu  = tid >> 6;
    const int quad = lane >> 4;
    const int col  = lane & 15;
    const int b    = blockIdx.x;
    const int oblk = blockIdx.y;
    const int o0   = oblk * 16;
    const int tw   = wvu * 64;

    if (tid < 68) {
        const int k = tid - 2;
        double v = 0.0;
        if (k >= 1 && k <= 61) {
            double wv = (double)k / 8.0 * exp(1.0 - (double)k / 8.0);
            v = (double)(float)wv;     // fp32-rounded tap, widened (R1-R25)
        }
        srmE[tid] = v;
    }

    // ---------------- phase 1: merged gemm (single K-loop) ------------------
    const signed char* Apg = planes + (size_t)oblk * NS * 5120 + lane * 16;
    const signed char* Bx  = bexp + (((size_t)b*(I/16) + quad)*256 + tw + col)*16;
    const double inv = 1.0 / 274877906944.0;             // 2^-38

    v4i acc[5][4];
    #pragma unroll
    for (int p = 0; p < 5; ++p)
        #pragma unroll
        for (int nt = 0; nt < 4; ++nt)
            acc[p][nt] = (v4i){0, 0, 0, 0};

    #pragma unroll 1
    for (int s = 0; s < NS; ++s) {
        v4i af[5];
        #pragma unroll
        for (int p = 0; p < 5; ++p)
            af[p] = *(const v4i*)(const void*)(Apg + (size_t)s * 5120 + p * 1024);
        v4i bf[4];
        #pragma unroll
        for (int nt = 0; nt < 4; ++nt)
            bf[nt] = *(const v4i*)(const void*)(Bx + (size_t)s * 16384 + nt * 256);

        #pragma unroll
        for (int nt = 0; nt < 4; ++nt)
            #pragma unroll
            for (int p = 0; p < 5; ++p)
                acc[p][nt] = __builtin_amdgcn_mfma_i32_16x16x64_i8(
                                 af[p], bf[nt], acc[p][nt], 0, 0, 0);
    }

    // recombine: exact fp64 a into LDS at swizzled column --------------------
    #pragma unroll
    for (int nt = 0; nt < 4; ++nt) {
        const int t = tw + nt*16 + col;
        const int cb = quad*4 + ((t & 3) << 2);          // wrap-free base
        #pragma unroll
        for (int r = 0; r < 4; ++r) {
            double v =            (double)acc[4][nt][r];
            v = v * 256.0 + (double)acc[3][nt][r];
            v = v * 256.0 + (double)acc[2][nt][r];
            v = v * 256.0 + (double)acc[1][nt][r];
            v = v * 256.0 + (double)acc[0][nt][r];
            a_lds[t * 17 + ((cb + r) & 15)] = v * inv;
        }
    }

    if (tid < 17) a_lds[256 * 17 + tid] = 0.0;           // zero-guard row
    __syncthreads();                                     // the only barrier

    // ---------------- phase 2: conv (swizzled-column reads) -----------------
    const int o    = tid & 15;
    const int tgrp = tid >> 4;                           // 0..15
    #pragma unroll 1
    for (int pass = 0; pass < 4; ++pass) {
        const int T0b = pass * 64 + tgrp * 4;
        double u0 = 0, u1 = 0, u2 = 0, u3 = 0;
        double w1 = srmE[64], w2 = srmE[65], w3 = srmE[66];   // zero pads
        for (int d = 0; d < 64; d += 4) {
            const int row = T0b - 61 + d;
            const int rr0 = (row + 0 < 0) ? 256 : row + 0;
            const int rr1 = (row + 1 < 0) ? 256 : row + 1;
            const int rr2 = (row + 2 < 0) ? 256 : row + 2;
            const int rr3 = (row + 3 < 0) ? 256 : row + 3;
            const double av0 = a_lds[rr0 * 17 + ((o + ((rr0 & 3) << 2)) & 15)];
            const double av1 = a_lds[rr1 * 17 + ((o + ((rr1 & 3) << 2)) & 15)];
            const double av2 = a_lds[rr2 * 17 + ((o + ((rr2 & 3) << 2)) & 15)];
            const double av3 = a_lds[rr3 * 17 + ((o + ((rr3 & 3) << 2)) & 15)];
            const double n0 = srmE[63 - d], n1 = srmE[62 - d];
            const double n2 = srmE[61 - d], n3 = srmE[60 - d];
            u0 = fma(n0, av0, u0); u1 = fma(w1, av0, u1); u2 = fma(w2, av0, u2); u3 = fma(w3, av0, u3);
            u0 = fma(n1, av1, u0); u1 = fma(n0, av1, u1); u2 = fma(w1, av1, u2); u3 = fma(w2, av1, u3);
            u0 = fma(n2, av2, u0); u1 = fma(n1, av2, u1); u2 = fma(n0, av2, u2); u3 = fma(w1, av2, u3);
            u0 = fma(n3, av3, u0); u1 = fma(n2, av3, u1); u2 = fma(n1, av3, u2); u3 = fma(n0, av3, u3);
            w1 = n3; w2 = n2; w3 = n1;
        }
        double* up = u + ((size_t)b * 256 + T0b) * OS + o0 + o;
        up[0]              = u0;
        up[(size_t)OS]     = u1;
        up[(size_t)OS * 2] = u2;
        up[(size_t)OS * 3] = u3;
    }
}

// ========================== scan (byte-table refractory) ====================
// lane = neuron; 256 sequential steps. Refractory via 8 independent LDS
// table lookups. u prefetch: 3-stage pipeline -- hold current 8 t + next
// 8 t, issue next-next 8 t (16-t lead covers ~900cy HBM at 1 wave/SIMD).
// FINAL=false: 256-thread blocks; ballots -> expanded i8 bexp_out.
// FINAL=true:  64-thread blocks, grid (8,32) -> all CUs; f32 out[b][o][t].
template<bool FINAL>
__global__ void scan_spikes(const double* __restrict__ u,
                            signed char* __restrict__ bexp_out,
                            float* __restrict__ f32_out, int OS)
{
    __shared__ double   ref64[KLEN];
    __shared__ double   tbl[8 * 256];   // 16 KB byte-sum tables
    __shared__ uint32_t blds[8][256];   // 8 KB ballot staging
    const int tid  = threadIdx.x;
    const int nthr = FINAL ? 64 : 256;

    if (tid < KLEN) {
        double v = (double)tid / 8.0 * exp(1.0 - (double)tid / 8.0);
        ref64[tid] = (double)(float)(-20.0 * v);
    }
    __syncthreads();
    for (int e = tid; e < 2048; e += nthr) {
        const int j = e >> 8, v = e & 255;
        double s = 0.0;
        #pragma unroll
        for (int i = 0; i < 8; ++i) {
            const int k = j * 8 + i + 1;
            if (k <= 61)
                s += ((v >> i) & 1) ? ref64[k] : 0.0;
        }
        tbl[e] = s;
    }
    __syncthreads();

    const int b     = blockIdx.y;
    const int obase = blockIdx.x * nthr;
    const int o     = obase + tid;
    const int lane  = tid & 63;
    const int wv    = tid >> 6;
    const double* up = u + (size_t)b * TT * OS + o;

    uint64_t mask = 0;
    // 3-stage prefetch: c = current 8 t, d = next 8 t; n issued in-loop
    double c0 = up[0],            c1 = up[OS],
           c2 = up[2*(size_t)OS], c3 = up[3*(size_t)OS],
           c4 = up[4*(size_t)OS], c5 = up[5*(size_t)OS],
           c6 = up[6*(size_t)OS], c7 = up[7*(size_t)OS];
    double d0 = up[ 8*(size_t)OS], d1 = up[ 9*(size_t)OS],
           d2 = up[10*(size_t)OS], d3 = up[11*(size_t)OS],
           d4 = up[12*(size_t)OS], d5 = up[13*(size_t)OS],
           d6 = up[14*(size_t)OS], d7 = up[15*(size_t)OS];
    for (int t0 = 0; t0 < TT; t0 += 8) {
        double n0 = 0, n1 = 0, n2 = 0, n3 = 0, n4 = 0, n5 = 0, n6 = 0, n7 = 0;
        if (t0 + 16 < TT) {
            const double* pp = up + (size_t)(t0 + 16) * OS;
            n0 = pp[0];            n1 = pp[OS];
            n2 = pp[2*(size_t)OS]; n3 = pp[3*(size_t)OS];
            n4 = pp[4*(size_t)OS]; n5 = pp[5*(size_t)OS];
            n6 = pp[6*(size_t)OS]; n7 = pp[7*(size_t)OS];
        }
        #pragma unroll
        for (int q = 0; q < 8; ++q) {
            const double uv = (q == 0) ? c0 : (q == 1) ? c1 : (q == 2) ? c2 :
                              (q == 3) ? c3 : (q == 4) ? c4 : (q == 5) ? c5 :
                              (q == 6) ? c6 : c7;
            const uint64_t m = mask;
            const double ra = tbl[        (int)( m        & 255)]
                            + tbl[256   + (int)((m >>  8) & 255)];
            const double rb = tbl[512   + (int)((m >> 16) & 255)]
                            + tbl[768   + (int)((m >> 24) & 255)];
            const double rc = tbl[1024  + (int)((m >> 32) & 255)]
                            + tbl[1280  + (int)((m >> 40) & 255)];
            const double rd = tbl[1536  + (int)((m >> 48) & 255)]
                            + tbl[1792  + (int)((m >> 56) & 255)];
            const double r  = (ra + rb) + (rc + rd);
            const bool s = (uv + r) >= THETA;
            const uint64_t bal = __ballot(s);
            if (lane == 0) {
                blds[wv * 2 + 0][t0 + q] = (uint32_t)bal;
                blds[wv * 2 + 1][t0 + q] = (uint32_t)(bal >> 32);
            }
            mask = ((mask << 1) | (s ? 1ull : 0ull)) & ((1ull << 61) - 1ull);
        }
        c0 = d0; c1 = d1; c2 = d2; c3 = d3; c4 = d4; c5 = d5; c6 = d6; c7 = d7;
        d0 = n0; d1 = n1; d2 = n2; d3 = n3; d4 = n4; d5 = n5; d6 = n6; d7 = n7;
    }
    __syncthreads();

    if (!FINAL) {
        // expand ballots to i8 B-matrix: entry g = obase/16 + gl, byte m =
        // bit ((gl&1)*16 + m) of word blds[gl>>1][t]  (i = g*16 + m)
        const int gbase = obase >> 4;
        for (int e = tid; e < 16 * 256; e += 256) {
            const int gl = e >> 8, t = e & 255;
            const uint32_t w = blds[gl >> 1][t];
            const uint32_t h = (w >> ((gl & 1) * 16)) & 0xFFFFu;
            uint32_t uu[4];
            #pragma unroll
            for (int j = 0; j < 4; ++j)
                uu[j] = (((h >> (4*j)) & 0xFu) * 0x00204081u) & 0x01010101u;
            *(uint4*)(bexp_out + (((size_t)b*128 + gbase + gl)*256 + t)*16) =
                *(const uint4*)uu;
        }
    } else {
        // 64-thread blocks: 64 neurons x 256 t, coalesced 256B rows
        for (int e = tid; e < 64 * 256; e += 64) {
            const int ol = e >> 8, tq = e & 255;
            const uint32_t w = blds[ol >> 5][tq];
            f32_out[((size_t)b * 512 + obase + ol) * TT + tq] =
                (float)((w >> (ol & 31)) & 1u);
        }
    }
}

// ================================ launcher ==================================
extern "C" void kernel_launch(void* const* d_in, const int* in_sizes, int n_in,
                              void* d_out, int out_size, void* d_ws, size_t ws_size,
                              hipStream_t stream)
{
    const float* x  = (const float*)d_in[0];   // [32][1024][256]
    const float* w1 = (const float*)d_in[1];   // [2048][1024]
    const float* w2 = (const float*)d_in[2];   // [512][2048]
    float* out = (float*)d_out;                // [32][512][256]

    char* ws = (char*)d_ws;
    // liveness-based layout (Bexp2 aliases dead P1/Bexp1): total ~158 MB
    signed char* P2    = (signed char*)ws;                      // 5.25 MB
    size_t roff = (size_t)32 * 32 * 5120;                       // 5242880
    signed char* P1    = (signed char*)(ws + roff);             // 10.5 MB
    signed char* Bexp1 = (signed char*)(ws + roff + (size_t)128*16*5120); // 8 MB
    signed char* Bexp2 = (signed char*)(ws + roff);             // 16 MB (alias)
    size_t uoff = roff + (size_t)128*16*5120 + (size_t)32*64*256*16; // 24117248
    double* uBuf = (double*)(ws + uoff);                        // 134 MB

    expand_x<<<dim3(32, 64), 256, 0, stream>>>(x, Bexp1);
    decompose_i8<<<dim3((10485760 + 255)/256), 256, 0, stream>>>(w1, P1, 1024, 10485760);
    decompose_i8<<<dim3((5242880  + 255)/256), 256, 0, stream>>>(w2, P2, 2048, 5242880);

    // layer 1: 1024 -> 2048  (fused gemm+conv: u written directly)
    fused_gc<1024><<<dim3(32, 128), 256, 0, stream>>>(Bexp1, P1, uBuf, 2048);
    scan_spikes<false><<<dim3(8, 32), 256, 0, stream>>>(uBuf, Bexp2, nullptr, 2048);
    // layer 2: 2048 -> 512
    fused_gc<2048><<<dim3(32, 32), 256, 0, stream>>>(Bexp2, P2, uBuf, 512);
    scan_spikes<true><<<dim3(8, 32), 64, 0, stream>>>(uBuf, nullptr, out, 512);
}